// Round 4
// baseline (789.264 us; speedup 1.0000x reference)
//
#include <hip/hip_runtime.h>

#define BS_TOTAL 32768   // B*S
#define DB 768
#define EPAD 64          // ent slab padded 50 -> 64
#define KV 832           // DB + EPAD (virtual K)
#define KREAL 818        // real K (cols >= 818 are zero)
#define TT 68
#define SEQ 512

typedef float v2f __attribute__((ext_vector_type(2)));
union F4 { float4 q; v2f h[2]; float f[4]; };

// packed fp32 fma: acc(pair) += broadcast(a.lo or a.hi) * b(pair)
#define PK_LO(acc, a, b) asm("v_pk_fma_f32 %0, %1, %2, %0 op_sel:[0,0,0] op_sel_hi:[0,1,1]" : "+v"(acc) : "v"(a), "v"(b))
#define PK_HI(acc, a, b) asm("v_pk_fma_f32 %0, %1, %2, %0 op_sel:[1,0,0] op_sel_hi:[1,1,1]" : "+v"(acc) : "v"(a), "v"(b))

// ---------------- K0: ent = sum_k entity_table[entities_x[...,k]] -> [32768][64]
__global__ __launch_bounds__(256) void ent_kernel(
    const int* __restrict__ ex, const float* __restrict__ table,
    float* __restrict__ entw)
{
    int g = blockIdx.x * 256 + threadIdx.x;
    int bs = g >> 6;
    int e = g & 63;
    float v = 0.f;
    if (e < 50) {
        int base = bs * 3;
        int i0 = ex[base], i1 = ex[base + 1], i2 = ex[base + 2];
        v = table[i0 * 50 + e] + table[i1 * 50 + e] + table[i2 * 50 + e];
    }
    entw[g] = v;
}

// ---------------- K1: x = relu(concat(enc, ent) @ W^T + b)  [32768][768]
// 128x128 tile, BK=32, 256 threads, 8 rows x 4 col-pairs per thread,
// register-prefetch single-LDS-buffer pipeline, v_pk_fma_f32 inner loop.
__global__ __launch_bounds__(256, 4) void fc1_gemm(
    const float* __restrict__ enc, const float* __restrict__ entw,
    const float* __restrict__ W, const float* __restrict__ bias,
    float* __restrict__ xout)
{
    __shared__ float As[32 * 132];
    __shared__ float Bs[32 * 132];
    const int t = threadIdx.x;
    const int bn0 = blockIdx.x * 128;   // N outer: consecutive blocks share A panel
    const int bm0 = blockIdx.y * 128;
    const int tx = t & 15, ty = t >> 4;

    v2f acc[8][4];
#pragma unroll
    for (int i = 0; i < 8; ++i)
#pragma unroll
        for (int p = 0; p < 4; ++p) acc[i][p] = (v2f){0.f, 0.f};

    float4 pA[4];
    float2 pB[8];

#define LOADA(IT) {                                                         \
    int k0_ = (IT) * 32;                                                    \
    _Pragma("unroll")                                                       \
    for (int i_ = 0; i_ < 4; ++i_) {                                        \
        int cid_ = t + i_ * 256;                                            \
        int r_ = cid_ >> 3;                                                 \
        int c4_ = (cid_ & 7) << 2;                                          \
        int k_ = k0_ + c4_;                                                 \
        int row_ = bm0 + r_;                                                \
        pA[i_] = (k_ < DB)                                                  \
            ? *reinterpret_cast<const float4*>(enc + (size_t)row_ * DB + k_)\
            : *reinterpret_cast<const float4*>(entw + ((size_t)row_ << 6) + (k_ - DB)); } }

#define LOADB(IT) {                                                         \
    int k0_ = (IT) * 32;                                                    \
    _Pragma("unroll")                                                       \
    for (int i_ = 0; i_ < 8; ++i_) {                                        \
        int cid_ = t + i_ * 256;                                            \
        int n_ = cid_ >> 4;                                                 \
        int c2_ = (cid_ & 15) << 1;                                         \
        int kg_ = k0_ + c2_;                                                \
        pB[i_] = (kg_ < KREAL)                                              \
            ? *reinterpret_cast<const float2*>(W + (size_t)(bn0 + n_) * KREAL + kg_) \
            : make_float2(0.f, 0.f); } }

    LOADA(0); LOADB(0);

    for (int it = 0; it < 26; ++it) {
        __syncthreads();
        // LDS stores (transposed [k][m])
#pragma unroll
        for (int i = 0; i < 4; ++i) {
            int cid = t + i * 256;
            int r = cid >> 3;
            int c4 = (cid & 7) << 2;
            As[(c4 + 0) * 132 + r] = pA[i].x;
            As[(c4 + 1) * 132 + r] = pA[i].y;
            As[(c4 + 2) * 132 + r] = pA[i].z;
            As[(c4 + 3) * 132 + r] = pA[i].w;
        }
#pragma unroll
        for (int i = 0; i < 8; ++i) {
            int cid = t + i * 256;
            int n = cid >> 4;
            int c2 = (cid & 15) << 1;
            Bs[(c2 + 0) * 132 + n] = pB[i].x;
            Bs[(c2 + 1) * 132 + n] = pB[i].y;
        }
        if (it < 25) { LOADA(it + 1); LOADB(it + 1); }  // prefetch overlaps compute
        __syncthreads();
#pragma unroll
        for (int kk = 0; kk < 32; ++kk) {
            const float* Ar = As + kk * 132 + ty * 8;
            const float* Br = Bs + kk * 132 + tx * 4;
            F4 a0, a1, b0, b1;
            a0.q = *reinterpret_cast<const float4*>(Ar);
            a1.q = *reinterpret_cast<const float4*>(Ar + 4);
            b0.q = *reinterpret_cast<const float4*>(Br);
            b1.q = *reinterpret_cast<const float4*>(Br + 64);
#define ROWPK(I, AH)                                                     \
            PK_LO(acc[I][0], AH, b0.h[0]); PK_LO(acc[I][1], AH, b0.h[1]);\
            PK_LO(acc[I][2], AH, b1.h[0]); PK_LO(acc[I][3], AH, b1.h[1]);\
            PK_HI(acc[I+1][0], AH, b0.h[0]); PK_HI(acc[I+1][1], AH, b0.h[1]);\
            PK_HI(acc[I+1][2], AH, b1.h[0]); PK_HI(acc[I+1][3], AH, b1.h[1]);
            ROWPK(0, a0.h[0]) ROWPK(2, a0.h[1]) ROWPK(4, a1.h[0]) ROWPK(6, a1.h[1])
#undef ROWPK
        }
    }

    float4 bias0 = *reinterpret_cast<const float4*>(bias + bn0 + tx * 4);
    float4 bias1 = *reinterpret_cast<const float4*>(bias + bn0 + 64 + tx * 4);
#pragma unroll
    for (int i = 0; i < 8; ++i) {
        size_t row = (size_t)(bm0 + ty * 8 + i);
        float4 o;
        o.x = fmaxf(acc[i][0].x + bias0.x, 0.f);
        o.y = fmaxf(acc[i][0].y + bias0.y, 0.f);
        o.z = fmaxf(acc[i][1].x + bias0.z, 0.f);
        o.w = fmaxf(acc[i][1].y + bias0.w, 0.f);
        *reinterpret_cast<float4*>(xout + row * DB + bn0 + tx * 4) = o;
        o.x = fmaxf(acc[i][2].x + bias1.x, 0.f);
        o.y = fmaxf(acc[i][2].y + bias1.y, 0.f);
        o.z = fmaxf(acc[i][3].x + bias1.z, 0.f);
        o.w = fmaxf(acc[i][3].y + bias1.w, 0.f);
        *reinterpret_cast<float4*>(xout + row * DB + bn0 + 64 + tx * 4) = o;
    }
}

// ---------------- K2: gathered trig GEMM + bias + argmax
// 32 rows/block (1024 blocks), 256 threads: tx 0..15 col-groups, ty 0..15 -> 2 rows
__global__ __launch_bounds__(256) void trig_kernel(
    const float* __restrict__ xfc, const int* __restrict__ head_idx,
    const float* __restrict__ Wt, const float* __restrict__ bt,
    float* __restrict__ logits, float* __restrict__ hat)
{
    __shared__ float Xs[32 * 36];   // [kk][row], 32 rows + 4 pad
    __shared__ float Ws[32 * 80];   // [kk][n], n>=68 zero
    __shared__ int srow[32];
    const int t = threadIdx.x;
    const int s0 = blockIdx.x * 32;
    if (t < 32) {
        int sg = s0 + t;
        int b = sg >> 9;
        srow[t] = (b << 9) + head_idx[sg];
    }
    __syncthreads();
    const int tx = t & 15, ty = t >> 4;
    float acc[2][5];
#pragma unroll
    for (int i = 0; i < 2; ++i)
#pragma unroll
        for (int m = 0; m < 5; ++m) acc[i][m] = 0.f;

    for (int k0 = 0; k0 < DB; k0 += 32) {
        // stage X: 32 rows x 32 k = 256 float4, 1/thread
        {
            int r = t >> 3;
            int c4 = (t & 7) << 2;
            float4 v = *reinterpret_cast<const float4*>(xfc + (size_t)srow[r] * DB + k0 + c4);
            Xs[(c4 + 0) * 36 + r] = v.x;
            Xs[(c4 + 1) * 36 + r] = v.y;
            Xs[(c4 + 2) * 36 + r] = v.z;
            Xs[(c4 + 3) * 36 + r] = v.w;
        }
        // stage W^T: 32 k x 80 n = 2560, 10/thread
#pragma unroll
        for (int i = 0; i < 10; ++i) {
            int e = t + i * 256;
            int kk = e & 31;
            int n = e >> 5;
            float v = (n < TT) ? Wt[(size_t)n * DB + k0 + kk] : 0.f;
            Ws[kk * 80 + n] = v;
        }
        __syncthreads();
#pragma unroll
        for (int kk = 0; kk < 32; ++kk) {
            v2f xa = *reinterpret_cast<const v2f*>(Xs + kk * 36 + ty * 2);
            float w[5];
#pragma unroll
            for (int m = 0; m < 5; ++m) w[m] = Ws[kk * 80 + tx + 16 * m];
#pragma unroll
            for (int m = 0; m < 5; ++m) {
                acc[0][m] += xa.x * w[m];
                acc[1][m] += xa.y * w[m];
            }
        }
        __syncthreads();
    }
#pragma unroll
    for (int i = 0; i < 2; ++i) {
        int row = s0 + ty * 2 + i;
        float bestv = -1e38f;
        int besti = 0;
#pragma unroll
        for (int m = 0; m < 5; ++m) {
            int col = tx + 16 * m;
            float v = -1e38f;
            if (col < TT) {
                v = acc[i][m] + bt[col];
                logits[(size_t)row * TT + col] = v;
            }
            if (v > bestv) { bestv = v; besti = col; }
        }
#pragma unroll
        for (int off = 8; off > 0; off >>= 1) {
            float ov = __shfl_xor(bestv, off, 16);
            int oi = __shfl_xor(besti, off, 16);
            if (ov > bestv || (ov == bestv && oi < besti)) { bestv = ov; besti = oi; }
        }
        if (tx == 0) hat[row] = (float)besti;
    }
}

// ---------------- K3a: span-mean pooling -> pooled[64][24][768]
__global__ __launch_bounds__(256) void pool_kernel(
    const float* __restrict__ xfc, const int* __restrict__ head_idx,
    const int* __restrict__ cand_spans, const int* __restrict__ trig_spans,
    float* __restrict__ pooled)
{
    const int b = blockIdx.x;
    __shared__ int rows_s[24][8];
    __shared__ int lens[24];
    __shared__ float invlen[24];
    const int t = threadIdx.x;
    if (t < 24) {
        const int* sp = (t < 8) ? (trig_spans + (b * 8 + t) * 2)
                                : (cand_spans + (b * 16 + (t - 8)) * 2);
        int st = sp[0], en = sp[1];
        int len = en - st;
        if (len < 0) len = 0;
        if (len > 8) len = 8;
        lens[t] = len;
        invlen[t] = 1.f / (float)(len > 0 ? len : 1);
        for (int p = 0; p < len; ++p)
            rows_s[t][p] = (b << 9) + head_idx[(b << 9) + st + p];
    }
    __syncthreads();
    for (int idx = t; idx < 24 * DB; idx += 256) {
        int n = idx / DB;
        int d = idx - n * DB;
        int len = lens[n];
        float s = 0.f;
        for (int p = 0; p < len; ++p)
            s += xfc[(size_t)rows_s[n][p] * DB + d];
        pooled[((size_t)b * 24 + n) * DB + d] = s * invlen[n];
    }
}

// ---------------- K3b: argument_hidden broadcast write [64][8][16][1536]
__global__ __launch_bounds__(256) void arg_kernel(
    const float* __restrict__ pooled, float* __restrict__ out2)
{
    int g = blockIdx.x * 256 + threadIdx.x;
    int b = g / 49152;
    int rem = g - b * 49152;
    int pair = rem / 384;
    int off4 = rem - pair * 384;
    int ti = pair >> 4;
    int c = pair & 15;
    int col = off4 << 2;
    const float* src;
    if (col < DB) src = pooled + ((size_t)(b * 24 + ti)) * DB + col;
    else          src = pooled + ((size_t)(b * 24 + 8 + c)) * DB + (col - DB);
    float4 v = *reinterpret_cast<const float4*>(src);
    *reinterpret_cast<float4*>(out2 + ((size_t)g << 2)) = v;
}

extern "C" void kernel_launch(void* const* d_in, const int* in_sizes, int n_in,
                              void* d_out, int out_size, void* d_ws, size_t ws_size,
                              hipStream_t stream)
{
    const float* enc   = (const float*)d_in[0];
    const float* table = (const float*)d_in[1];
    const float* fc1w  = (const float*)d_in[2];
    const float* fc1b  = (const float*)d_in[3];
    const float* trigw = (const float*)d_in[4];
    const float* trigb = (const float*)d_in[5];
    const int*   ex    = (const int*)d_in[6];
    const int*   hidx  = (const int*)d_in[7];
    const int*   cspan = (const int*)d_in[8];
    const int*   tspan = (const int*)d_in[9];

    float* out0 = (float*)d_out;
    float* out1 = out0 + (size_t)BS_TOTAL * TT;
    float* out2 = out1 + BS_TOTAL;

    float* ws_ent  = (float*)d_ws;
    float* ws_xfc  = ws_ent + (size_t)BS_TOTAL * EPAD;
    float* ws_pool = ws_xfc + (size_t)BS_TOTAL * DB;

    ent_kernel<<<dim3(BS_TOTAL * EPAD / 256), dim3(256), 0, stream>>>(ex, table, ws_ent);
    fc1_gemm<<<dim3(DB / 128, BS_TOTAL / 128), dim3(256), 0, stream>>>(enc, ws_ent, fc1w, fc1b, ws_xfc);
    trig_kernel<<<dim3(BS_TOTAL / 32), dim3(256), 0, stream>>>(ws_xfc, hidx, trigw, trigb, out0, out1);
    pool_kernel<<<dim3(64), dim3(256), 0, stream>>>(ws_xfc, hidx, cspan, tspan, ws_pool);
    arg_kernel<<<dim3(3145728 / 256), dim3(256), 0, stream>>>(ws_pool, out2);
}

// Round 5
// 786.563 us; speedup vs baseline: 1.0034x; 1.0034x over previous
//
#include <hip/hip_runtime.h>

#define BS_TOTAL 32768   // B*S
#define DB 768
#define EPAD 64          // ent slab padded 50 -> 64
#define KV 832           // DB + EPAD (virtual K)
#define KREAL 818        // real K (cols >= 818 are zero)
#define TT 68
#define SEQ 512

typedef float v2f __attribute__((ext_vector_type(2)));
union F4 { float4 q; v2f h[2]; float f[4]; };

// packed fp32 fma: acc(pair) += broadcast(a.lo or a.hi) * b(pair)
#define PK_LO(acc, a, b) asm("v_pk_fma_f32 %0, %1, %2, %0 op_sel:[0,0,0] op_sel_hi:[0,1,1]" : "+v"(acc) : "v"(a), "v"(b))
#define PK_HI(acc, a, b) asm("v_pk_fma_f32 %0, %1, %2, %0 op_sel:[1,0,0] op_sel_hi:[1,1,1]" : "+v"(acc) : "v"(a), "v"(b))

// ---------------- K0: ent = sum_k entity_table[entities_x[...,k]] -> [32768][64]
__global__ __launch_bounds__(256) void ent_kernel(
    const int* __restrict__ ex, const float* __restrict__ table,
    float* __restrict__ entw)
{
    int g = blockIdx.x * 256 + threadIdx.x;
    int bs = g >> 6;
    int e = g & 63;
    float v = 0.f;
    if (e < 50) {
        int base = bs * 3;
        int i0 = ex[base], i1 = ex[base + 1], i2 = ex[base + 2];
        v = table[i0 * 50 + e] + table[i1 * 50 + e] + table[i2 * 50 + e];
    }
    entw[g] = v;
}

// ---------------- K1: x = relu(concat(enc, ent) @ W^T + b)  [32768][768]
// 128x128 tile, BK=32, 256 threads, 8 rows x 4 col-pairs per thread,
// register-prefetch single-LDS-buffer pipeline, v_pk_fma_f32 inner loop.
__global__ __launch_bounds__(256, 4) void fc1_gemm(
    const float* __restrict__ enc, const float* __restrict__ entw,
    const float* __restrict__ W, const float* __restrict__ bias,
    float* __restrict__ xout)
{
    __shared__ float As[32 * 132];
    __shared__ float Bs[32 * 132];
    const int t = threadIdx.x;
    const int bn0 = blockIdx.x * 128;   // N outer: consecutive blocks share A panel
    const int bm0 = blockIdx.y * 128;
    const int tx = t & 15, ty = t >> 4;

    v2f acc[8][4];
#pragma unroll
    for (int i = 0; i < 8; ++i)
#pragma unroll
        for (int p = 0; p < 4; ++p) acc[i][p] = (v2f){0.f, 0.f};

    float4 pA[4];
    float2 pB[8];

#define LOADA(IT) {                                                         \
    int k0_ = (IT) * 32;                                                    \
    _Pragma("unroll")                                                       \
    for (int i_ = 0; i_ < 4; ++i_) {                                        \
        int cid_ = t + i_ * 256;                                            \
        int r_ = cid_ >> 3;                                                 \
        int c4_ = (cid_ & 7) << 2;                                          \
        int k_ = k0_ + c4_;                                                 \
        int row_ = bm0 + r_;                                                \
        pA[i_] = (k_ < DB)                                                  \
            ? *reinterpret_cast<const float4*>(enc + (size_t)row_ * DB + k_)\
            : *reinterpret_cast<const float4*>(entw + ((size_t)row_ << 6) + (k_ - DB)); } }

#define LOADB(IT) {                                                         \
    int k0_ = (IT) * 32;                                                    \
    _Pragma("unroll")                                                       \
    for (int i_ = 0; i_ < 8; ++i_) {                                        \
        int cid_ = t + i_ * 256;                                            \
        int n_ = cid_ >> 4;                                                 \
        int c2_ = (cid_ & 15) << 1;                                         \
        int kg_ = k0_ + c2_;                                                \
        pB[i_] = (kg_ < KREAL)                                              \
            ? *reinterpret_cast<const float2*>(W + (size_t)(bn0 + n_) * KREAL + kg_) \
            : make_float2(0.f, 0.f); } }

    LOADA(0); LOADB(0);

    for (int it = 0; it < 26; ++it) {
        __syncthreads();
        // LDS stores (transposed [k][m])
#pragma unroll
        for (int i = 0; i < 4; ++i) {
            int cid = t + i * 256;
            int r = cid >> 3;
            int c4 = (cid & 7) << 2;
            As[(c4 + 0) * 132 + r] = pA[i].x;
            As[(c4 + 1) * 132 + r] = pA[i].y;
            As[(c4 + 2) * 132 + r] = pA[i].z;
            As[(c4 + 3) * 132 + r] = pA[i].w;
        }
#pragma unroll
        for (int i = 0; i < 8; ++i) {
            int cid = t + i * 256;
            int n = cid >> 4;
            int c2 = (cid & 15) << 1;
            Bs[(c2 + 0) * 132 + n] = pB[i].x;
            Bs[(c2 + 1) * 132 + n] = pB[i].y;
        }
        if (it < 25) { LOADA(it + 1); LOADB(it + 1); }  // prefetch overlaps compute
        __syncthreads();
#pragma unroll
        for (int kk = 0; kk < 32; ++kk) {
            const float* Ar = As + kk * 132 + ty * 8;
            const float* Br = Bs + kk * 132 + tx * 4;
            F4 a0, a1, b0, b1;
            a0.q = *reinterpret_cast<const float4*>(Ar);
            a1.q = *reinterpret_cast<const float4*>(Ar + 4);
            b0.q = *reinterpret_cast<const float4*>(Br);
            b1.q = *reinterpret_cast<const float4*>(Br + 64);
#define ROWPK(I, AH)                                                     \
            PK_LO(acc[I][0], AH, b0.h[0]); PK_LO(acc[I][1], AH, b0.h[1]);\
            PK_LO(acc[I][2], AH, b1.h[0]); PK_LO(acc[I][3], AH, b1.h[1]);\
            PK_HI(acc[I+1][0], AH, b0.h[0]); PK_HI(acc[I+1][1], AH, b0.h[1]);\
            PK_HI(acc[I+1][2], AH, b1.h[0]); PK_HI(acc[I+1][3], AH, b1.h[1]);
            ROWPK(0, a0.h[0]) ROWPK(2, a0.h[1]) ROWPK(4, a1.h[0]) ROWPK(6, a1.h[1])
#undef ROWPK
        }
    }

    float4 bias0 = *reinterpret_cast<const float4*>(bias + bn0 + tx * 4);
    float4 bias1 = *reinterpret_cast<const float4*>(bias + bn0 + 64 + tx * 4);
#pragma unroll
    for (int i = 0; i < 8; ++i) {
        size_t row = (size_t)(bm0 + ty * 8 + i);
        float4 o;
        o.x = fmaxf(acc[i][0].x + bias0.x, 0.f);
        o.y = fmaxf(acc[i][0].y + bias0.y, 0.f);
        o.z = fmaxf(acc[i][1].x + bias0.z, 0.f);
        o.w = fmaxf(acc[i][1].y + bias0.w, 0.f);
        *reinterpret_cast<float4*>(xout + row * DB + bn0 + tx * 4) = o;
        o.x = fmaxf(acc[i][2].x + bias1.x, 0.f);
        o.y = fmaxf(acc[i][2].y + bias1.y, 0.f);
        o.z = fmaxf(acc[i][3].x + bias1.z, 0.f);
        o.w = fmaxf(acc[i][3].y + bias1.w, 0.f);
        *reinterpret_cast<float4*>(xout + row * DB + bn0 + 64 + tx * 4) = o;
    }
}

// ---------------- K2: gathered trig GEMM + bias + argmax
// 32 rows/block (1024 blocks), 256 threads: tx 0..15 col-groups, ty 0..15 -> 2 rows
__global__ __launch_bounds__(256) void trig_kernel(
    const float* __restrict__ xfc, const int* __restrict__ head_idx,
    const float* __restrict__ Wt, const float* __restrict__ bt,
    float* __restrict__ logits, float* __restrict__ hat)
{
    __shared__ float Xs[32 * 36];   // [kk][row], 32 rows + 4 pad
    __shared__ float Ws[32 * 80];   // [kk][n], n>=68 zero
    __shared__ int srow[32];
    const int t = threadIdx.x;
    const int s0 = blockIdx.x * 32;
    if (t < 32) {
        int sg = s0 + t;
        int b = sg >> 9;
        srow[t] = (b << 9) + head_idx[sg];
    }
    __syncthreads();
    const int tx = t & 15, ty = t >> 4;
    float acc[2][5];
#pragma unroll
    for (int i = 0; i < 2; ++i)
#pragma unroll
        for (int m = 0; m < 5; ++m) acc[i][m] = 0.f;

    for (int k0 = 0; k0 < DB; k0 += 32) {
        // stage X: 32 rows x 32 k = 256 float4, 1/thread
        {
            int r = t >> 3;
            int c4 = (t & 7) << 2;
            float4 v = *reinterpret_cast<const float4*>(xfc + (size_t)srow[r] * DB + k0 + c4);
            Xs[(c4 + 0) * 36 + r] = v.x;
            Xs[(c4 + 1) * 36 + r] = v.y;
            Xs[(c4 + 2) * 36 + r] = v.z;
            Xs[(c4 + 3) * 36 + r] = v.w;
        }
        // stage W^T: 32 k x 80 n = 2560, 10/thread
#pragma unroll
        for (int i = 0; i < 10; ++i) {
            int e = t + i * 256;
            int kk = e & 31;
            int n = e >> 5;
            float v = (n < TT) ? Wt[(size_t)n * DB + k0 + kk] : 0.f;
            Ws[kk * 80 + n] = v;
        }
        __syncthreads();
#pragma unroll
        for (int kk = 0; kk < 32; ++kk) {
            v2f xa = *reinterpret_cast<const v2f*>(Xs + kk * 36 + ty * 2);
            float w[5];
#pragma unroll
            for (int m = 0; m < 5; ++m) w[m] = Ws[kk * 80 + tx + 16 * m];
#pragma unroll
            for (int m = 0; m < 5; ++m) {
                acc[0][m] += xa.x * w[m];
                acc[1][m] += xa.y * w[m];
            }
        }
        __syncthreads();
    }
#pragma unroll
    for (int i = 0; i < 2; ++i) {
        int row = s0 + ty * 2 + i;
        float bestv = -1e38f;
        int besti = 0;
#pragma unroll
        for (int m = 0; m < 5; ++m) {
            int col = tx + 16 * m;
            float v = -1e38f;
            if (col < TT) {
                v = acc[i][m] + bt[col];
                logits[(size_t)row * TT + col] = v;
            }
            if (v > bestv) { bestv = v; besti = col; }
        }
#pragma unroll
        for (int off = 8; off > 0; off >>= 1) {
            float ov = __shfl_xor(bestv, off, 16);
            int oi = __shfl_xor(besti, off, 16);
            if (ov > bestv || (ov == bestv && oi < besti)) { bestv = ov; besti = oi; }
        }
        if (tx == 0) hat[row] = (float)besti;
    }
}

// ---------------- K3a: span-mean pooling -> pooled[64][24][768]
__global__ __launch_bounds__(256) void pool_kernel(
    const float* __restrict__ xfc, const int* __restrict__ head_idx,
    const int* __restrict__ cand_spans, const int* __restrict__ trig_spans,
    float* __restrict__ pooled)
{
    const int b = blockIdx.x;
    __shared__ int rows_s[24][8];
    __shared__ int lens[24];
    __shared__ float invlen[24];
    const int t = threadIdx.x;
    if (t < 24) {
        const int* sp = (t < 8) ? (trig_spans + (b * 8 + t) * 2)
                                : (cand_spans + (b * 16 + (t - 8)) * 2);
        int st = sp[0], en = sp[1];
        int len = en - st;
        if (len < 0) len = 0;
        if (len > 8) len = 8;
        lens[t] = len;
        invlen[t] = 1.f / (float)(len > 0 ? len : 1);
        for (int p = 0; p < len; ++p)
            rows_s[t][p] = (b << 9) + head_idx[(b << 9) + st + p];
    }
    __syncthreads();
    for (int idx = t; idx < 24 * DB; idx += 256) {
        int n = idx / DB;
        int d = idx - n * DB;
        int len = lens[n];
        float s = 0.f;
        for (int p = 0; p < len; ++p)
            s += xfc[(size_t)rows_s[n][p] * DB + d];
        pooled[((size_t)b * 24 + n) * DB + d] = s * invlen[n];
    }
}

// ---------------- K3b: argument_hidden broadcast write [64][8][16][1536]
__global__ __launch_bounds__(256) void arg_kernel(
    const float* __restrict__ pooled, float* __restrict__ out2)
{
    int g = blockIdx.x * 256 + threadIdx.x;
    int b = g / 49152;
    int rem = g - b * 49152;
    int pair = rem / 384;
    int off4 = rem - pair * 384;
    int ti = pair >> 4;
    int c = pair & 15;
    int col = off4 << 2;
    const float* src;
    if (col < DB) src = pooled + ((size_t)(b * 24 + ti)) * DB + col;
    else          src = pooled + ((size_t)(b * 24 + 8 + c)) * DB + (col - DB);
    float4 v = *reinterpret_cast<const float4*>(src);
    *reinterpret_cast<float4*>(out2 + ((size_t)g << 2)) = v;
}

extern "C" void kernel_launch(void* const* d_in, const int* in_sizes, int n_in,
                              void* d_out, int out_size, void* d_ws, size_t ws_size,
                              hipStream_t stream)
{
    const float* enc   = (const float*)d_in[0];
    const float* table = (const float*)d_in[1];
    const float* fc1w  = (const float*)d_in[2];
    const float* fc1b  = (const float*)d_in[3];
    const float* trigw = (const float*)d_in[4];
    const float* trigb = (const float*)d_in[5];
    const int*   ex    = (const int*)d_in[6];
    const int*   hidx  = (const int*)d_in[7];
    const int*   cspan = (const int*)d_in[8];
    const int*   tspan = (const int*)d_in[9];

    float* out0 = (float*)d_out;
    float* out1 = out0 + (size_t)BS_TOTAL * TT;
    float* out2 = out1 + BS_TOTAL;

    float* ws_ent  = (float*)d_ws;
    float* ws_xfc  = ws_ent + (size_t)BS_TOTAL * EPAD;
    float* ws_pool = ws_xfc + (size_t)BS_TOTAL * DB;

    ent_kernel<<<dim3(BS_TOTAL * EPAD / 256), dim3(256), 0, stream>>>(ex, table, ws_ent);
    fc1_gemm<<<dim3(DB / 128, BS_TOTAL / 128), dim3(256), 0, stream>>>(enc, ws_ent, fc1w, fc1b, ws_xfc);
    trig_kernel<<<dim3(BS_TOTAL / 32), dim3(256), 0, stream>>>(ws_xfc, hidx, trigw, trigb, out0, out1);
    pool_kernel<<<dim3(64), dim3(256), 0, stream>>>(ws_xfc, hidx, cspan, tspan, ws_pool);
    arg_kernel<<<dim3(3145728 / 256), dim3(256), 0, stream>>>(ws_pool, out2);
}

// Round 6
// 786.135 us; speedup vs baseline: 1.0040x; 1.0005x over previous
//
#include <hip/hip_runtime.h>

#define BS_TOTAL 32768   // B*S
#define DB 768
#define EPAD 64          // ent slab padded 50 -> 64
#define KV 832           // DB + EPAD (virtual K)
#define KREAL 818        // real K (cols >= 818 are zero)
#define TT 68
#define SEQ 512

typedef float v2f __attribute__((ext_vector_type(2)));
union F4 { float4 q; v2f h[2]; float f[4]; };

// packed fp32 fma: acc(pair) += broadcast(a.lo or a.hi) * b(pair)
#define PK_LO(acc, a, b) asm("v_pk_fma_f32 %0, %1, %2, %0 op_sel:[0,0,0] op_sel_hi:[0,1,1]" : "+v"(acc) : "v"(a), "v"(b))
#define PK_HI(acc, a, b) asm("v_pk_fma_f32 %0, %1, %2, %0 op_sel:[1,0,0] op_sel_hi:[1,1,1]" : "+v"(acc) : "v"(a), "v"(b))

// ---------------- K0: ent = sum_k entity_table[entities_x[...,k]] -> [32768][64]
__global__ __launch_bounds__(256) void ent_kernel(
    const int* __restrict__ ex, const float* __restrict__ table,
    float* __restrict__ entw)
{
    int g = blockIdx.x * 256 + threadIdx.x;
    int bs = g >> 6;
    int e = g & 63;
    float v = 0.f;
    if (e < 50) {
        int base = bs * 3;
        int i0 = ex[base], i1 = ex[base + 1], i2 = ex[base + 2];
        v = table[i0 * 50 + e] + table[i1 * 50 + e] + table[i2 * 50 + e];
    }
    entw[g] = v;
}

// ---------------- K1: x = relu(concat(enc, ent) @ W^T + b)  [32768][768]
// 128x128 tile, BK=32, 256 threads, 8 rows x 4 col-pairs per thread,
// register-prefetch single-LDS-buffer pipeline, v_pk_fma_f32 inner loop.
__global__ __launch_bounds__(256, 4) void fc1_gemm(
    const float* __restrict__ enc, const float* __restrict__ entw,
    const float* __restrict__ W, const float* __restrict__ bias,
    float* __restrict__ xout)
{
    __shared__ float As[32 * 132];
    __shared__ float Bs[32 * 132];
    const int t = threadIdx.x;
    const int bn0 = blockIdx.x * 128;   // N outer: consecutive blocks share A panel
    const int bm0 = blockIdx.y * 128;
    const int tx = t & 15, ty = t >> 4;

    v2f acc[8][4];
#pragma unroll
    for (int i = 0; i < 8; ++i)
#pragma unroll
        for (int p = 0; p < 4; ++p) acc[i][p] = (v2f){0.f, 0.f};

    float4 pA[4];
    float2 pB[8];

#define LOADA(IT) {                                                         \
    int k0_ = (IT) * 32;                                                    \
    _Pragma("unroll")                                                       \
    for (int i_ = 0; i_ < 4; ++i_) {                                        \
        int cid_ = t + i_ * 256;                                            \
        int r_ = cid_ >> 3;                                                 \
        int c4_ = (cid_ & 7) << 2;                                          \
        int k_ = k0_ + c4_;                                                 \
        int row_ = bm0 + r_;                                                \
        pA[i_] = (k_ < DB)                                                  \
            ? *reinterpret_cast<const float4*>(enc + (size_t)row_ * DB + k_)\
            : *reinterpret_cast<const float4*>(entw + ((size_t)row_ << 6) + (k_ - DB)); } }

#define LOADB(IT) {                                                         \
    int k0_ = (IT) * 32;                                                    \
    _Pragma("unroll")                                                       \
    for (int i_ = 0; i_ < 8; ++i_) {                                        \
        int cid_ = t + i_ * 256;                                            \
        int n_ = cid_ >> 4;                                                 \
        int c2_ = (cid_ & 15) << 1;                                         \
        int kg_ = k0_ + c2_;                                                \
        pB[i_] = (kg_ < KREAL)                                              \
            ? *reinterpret_cast<const float2*>(W + (size_t)(bn0 + n_) * KREAL + kg_) \
            : make_float2(0.f, 0.f); } }

    LOADA(0); LOADB(0);

    for (int it = 0; it < 26; ++it) {
        __syncthreads();
        // LDS stores (transposed [k][m])
#pragma unroll
        for (int i = 0; i < 4; ++i) {
            int cid = t + i * 256;
            int r = cid >> 3;
            int c4 = (cid & 7) << 2;
            As[(c4 + 0) * 132 + r] = pA[i].x;
            As[(c4 + 1) * 132 + r] = pA[i].y;
            As[(c4 + 2) * 132 + r] = pA[i].z;
            As[(c4 + 3) * 132 + r] = pA[i].w;
        }
#pragma unroll
        for (int i = 0; i < 8; ++i) {
            int cid = t + i * 256;
            int n = cid >> 4;
            int c2 = (cid & 15) << 1;
            Bs[(c2 + 0) * 132 + n] = pB[i].x;
            Bs[(c2 + 1) * 132 + n] = pB[i].y;
        }
        if (it < 25) { LOADA(it + 1); LOADB(it + 1); }  // prefetch overlaps compute
        __syncthreads();
#pragma unroll
        for (int kk = 0; kk < 32; ++kk) {
            const float* Ar = As + kk * 132 + ty * 8;
            const float* Br = Bs + kk * 132 + tx * 4;
            F4 a0, a1, b0, b1;
            a0.q = *reinterpret_cast<const float4*>(Ar);
            a1.q = *reinterpret_cast<const float4*>(Ar + 4);
            b0.q = *reinterpret_cast<const float4*>(Br);
            b1.q = *reinterpret_cast<const float4*>(Br + 64);
#define ROWPK(I, AH)                                                     \
            PK_LO(acc[I][0], AH, b0.h[0]); PK_LO(acc[I][1], AH, b0.h[1]);\
            PK_LO(acc[I][2], AH, b1.h[0]); PK_LO(acc[I][3], AH, b1.h[1]);\
            PK_HI(acc[I+1][0], AH, b0.h[0]); PK_HI(acc[I+1][1], AH, b0.h[1]);\
            PK_HI(acc[I+1][2], AH, b1.h[0]); PK_HI(acc[I+1][3], AH, b1.h[1]);
            ROWPK(0, a0.h[0]) ROWPK(2, a0.h[1]) ROWPK(4, a1.h[0]) ROWPK(6, a1.h[1])
#undef ROWPK
        }
    }

    float4 bias0 = *reinterpret_cast<const float4*>(bias + bn0 + tx * 4);
    float4 bias1 = *reinterpret_cast<const float4*>(bias + bn0 + 64 + tx * 4);
#pragma unroll
    for (int i = 0; i < 8; ++i) {
        size_t row = (size_t)(bm0 + ty * 8 + i);
        float4 o;
        o.x = fmaxf(acc[i][0].x + bias0.x, 0.f);
        o.y = fmaxf(acc[i][0].y + bias0.y, 0.f);
        o.z = fmaxf(acc[i][1].x + bias0.z, 0.f);
        o.w = fmaxf(acc[i][1].y + bias0.w, 0.f);
        *reinterpret_cast<float4*>(xout + row * DB + bn0 + tx * 4) = o;
        o.x = fmaxf(acc[i][2].x + bias1.x, 0.f);
        o.y = fmaxf(acc[i][2].y + bias1.y, 0.f);
        o.z = fmaxf(acc[i][3].x + bias1.z, 0.f);
        o.w = fmaxf(acc[i][3].y + bias1.w, 0.f);
        *reinterpret_cast<float4*>(xout + row * DB + bn0 + 64 + tx * 4) = o;
    }
}

// ---------------- K2: gathered trig GEMM + bias + argmax
// 32 rows/block (1024 blocks), 256 threads: tx 0..15 col-groups, ty 0..15 -> 2 rows
__global__ __launch_bounds__(256) void trig_kernel(
    const float* __restrict__ xfc, const int* __restrict__ head_idx,
    const float* __restrict__ Wt, const float* __restrict__ bt,
    float* __restrict__ logits, float* __restrict__ hat)
{
    __shared__ float Xs[32 * 36];   // [kk][row], 32 rows + 4 pad
    __shared__ float Ws[32 * 80];   // [kk][n], n>=68 zero
    __shared__ int srow[32];
    const int t = threadIdx.x;
    const int s0 = blockIdx.x * 32;
    if (t < 32) {
        int sg = s0 + t;
        int b = sg >> 9;
        srow[t] = (b << 9) + head_idx[sg];
    }
    __syncthreads();
    const int tx = t & 15, ty = t >> 4;
    float acc[2][5];
#pragma unroll
    for (int i = 0; i < 2; ++i)
#pragma unroll
        for (int m = 0; m < 5; ++m) acc[i][m] = 0.f;

    for (int k0 = 0; k0 < DB; k0 += 32) {
        // stage X: 32 rows x 32 k = 256 float4, 1/thread
        {
            int r = t >> 3;
            int c4 = (t & 7) << 2;
            float4 v = *reinterpret_cast<const float4*>(xfc + (size_t)srow[r] * DB + k0 + c4);
            Xs[(c4 + 0) * 36 + r] = v.x;
            Xs[(c4 + 1) * 36 + r] = v.y;
            Xs[(c4 + 2) * 36 + r] = v.z;
            Xs[(c4 + 3) * 36 + r] = v.w;
        }
        // stage W^T: 32 k x 80 n = 2560, 10/thread
#pragma unroll
        for (int i = 0; i < 10; ++i) {
            int e = t + i * 256;
            int kk = e & 31;
            int n = e >> 5;
            float v = (n < TT) ? Wt[(size_t)n * DB + k0 + kk] : 0.f;
            Ws[kk * 80 + n] = v;
        }
        __syncthreads();
#pragma unroll
        for (int kk = 0; kk < 32; ++kk) {
            v2f xa = *reinterpret_cast<const v2f*>(Xs + kk * 36 + ty * 2);
            float w[5];
#pragma unroll
            for (int m = 0; m < 5; ++m) w[m] = Ws[kk * 80 + tx + 16 * m];
#pragma unroll
            for (int m = 0; m < 5; ++m) {
                acc[0][m] += xa.x * w[m];
                acc[1][m] += xa.y * w[m];
            }
        }
        __syncthreads();
    }
#pragma unroll
    for (int i = 0; i < 2; ++i) {
        int row = s0 + ty * 2 + i;
        float bestv = -1e38f;
        int besti = 0;
#pragma unroll
        for (int m = 0; m < 5; ++m) {
            int col = tx + 16 * m;
            float v = -1e38f;
            if (col < TT) {
                v = acc[i][m] + bt[col];
                logits[(size_t)row * TT + col] = v;
            }
            if (v > bestv) { bestv = v; besti = col; }
        }
#pragma unroll
        for (int off = 8; off > 0; off >>= 1) {
            float ov = __shfl_xor(bestv, off, 16);
            int oi = __shfl_xor(besti, off, 16);
            if (ov > bestv || (ov == bestv && oi < besti)) { bestv = ov; besti = oi; }
        }
        if (tx == 0) hat[row] = (float)besti;
    }
}

// ---------------- K3a: span-mean pooling -> pooled[64][24][768]
__global__ __launch_bounds__(256) void pool_kernel(
    const float* __restrict__ xfc, const int* __restrict__ head_idx,
    const int* __restrict__ cand_spans, const int* __restrict__ trig_spans,
    float* __restrict__ pooled)
{
    const int b = blockIdx.x;
    __shared__ int rows_s[24][8];
    __shared__ int lens[24];
    __shared__ float invlen[24];
    const int t = threadIdx.x;
    if (t < 24) {
        const int* sp = (t < 8) ? (trig_spans + (b * 8 + t) * 2)
                                : (cand_spans + (b * 16 + (t - 8)) * 2);
        int st = sp[0], en = sp[1];
        int len = en - st;
        if (len < 0) len = 0;
        if (len > 8) len = 8;
        lens[t] = len;
        invlen[t] = 1.f / (float)(len > 0 ? len : 1);
        for (int p = 0; p < len; ++p)
            rows_s[t][p] = (b << 9) + head_idx[(b << 9) + st + p];
    }
    __syncthreads();
    for (int idx = t; idx < 24 * DB; idx += 256) {
        int n = idx / DB;
        int d = idx - n * DB;
        int len = lens[n];
        float s = 0.f;
        for (int p = 0; p < len; ++p)
            s += xfc[(size_t)rows_s[n][p] * DB + d];
        pooled[((size_t)b * 24 + n) * DB + d] = s * invlen[n];
    }
}

// ---------------- K3b: argument_hidden broadcast write [64][8][16][1536]
__global__ __launch_bounds__(256) void arg_kernel(
    const float* __restrict__ pooled, float* __restrict__ out2)
{
    int g = blockIdx.x * 256 + threadIdx.x;
    int b = g / 49152;
    int rem = g - b * 49152;
    int pair = rem / 384;
    int off4 = rem - pair * 384;
    int ti = pair >> 4;
    int c = pair & 15;
    int col = off4 << 2;
    const float* src;
    if (col < DB) src = pooled + ((size_t)(b * 24 + ti)) * DB + col;
    else          src = pooled + ((size_t)(b * 24 + 8 + c)) * DB + (col - DB);
    float4 v = *reinterpret_cast<const float4*>(src);
    *reinterpret_cast<float4*>(out2 + ((size_t)g << 2)) = v;
}

extern "C" void kernel_launch(void* const* d_in, const int* in_sizes, int n_in,
                              void* d_out, int out_size, void* d_ws, size_t ws_size,
                              hipStream_t stream)
{
    const float* enc   = (const float*)d_in[0];
    const float* table = (const float*)d_in[1];
    const float* fc1w  = (const float*)d_in[2];
    const float* fc1b  = (const float*)d_in[3];
    const float* trigw = (const float*)d_in[4];
    const float* trigb = (const float*)d_in[5];
    const int*   ex    = (const int*)d_in[6];
    const int*   hidx  = (const int*)d_in[7];
    const int*   cspan = (const int*)d_in[8];
    const int*   tspan = (const int*)d_in[9];

    float* out0 = (float*)d_out;
    float* out1 = out0 + (size_t)BS_TOTAL * TT;
    float* out2 = out1 + BS_TOTAL;

    float* ws_ent  = (float*)d_ws;
    float* ws_xfc  = ws_ent + (size_t)BS_TOTAL * EPAD;
    float* ws_pool = ws_xfc + (size_t)BS_TOTAL * DB;

    ent_kernel<<<dim3(BS_TOTAL * EPAD / 256), dim3(256), 0, stream>>>(ex, table, ws_ent);
    fc1_gemm<<<dim3(DB / 128, BS_TOTAL / 128), dim3(256), 0, stream>>>(enc, ws_ent, fc1w, fc1b, ws_xfc);
    trig_kernel<<<dim3(BS_TOTAL / 32), dim3(256), 0, stream>>>(ws_xfc, hidx, trigw, trigb, out0, out1);
    pool_kernel<<<dim3(64), dim3(256), 0, stream>>>(ws_xfc, hidx, cspan, tspan, ws_pool);
    arg_kernel<<<dim3(3145728 / 256), dim3(256), 0, stream>>>(ws_pool, out2);
}

// Round 7
// 438.332 us; speedup vs baseline: 1.8006x; 1.7935x over previous
//
#include <hip/hip_runtime.h>

#define BS_TOTAL 32768   // B*S
#define DB 768
#define KV 832           // padded K: 768 enc + 50 ent + 14 zero
#define KREAL 818
#define TT 68
#define SEQ 512

typedef float v2f __attribute__((ext_vector_type(2)));
typedef float f32x4 __attribute__((ext_vector_type(4)));
typedef _Float16 f16x8 __attribute__((ext_vector_type(8)));
typedef _Float16 f16x4 __attribute__((ext_vector_type(4)));

// ---------------- K0: split W into scaled fp16 hi/lo: W0+W1 = W*1024 (exact emu split)
__global__ __launch_bounds__(256) void splitw_kernel(
    const float* __restrict__ W, _Float16* __restrict__ W0, _Float16* __restrict__ W1)
{
    int row = blockIdx.x;
    int c4 = threadIdx.x * 4;
    if (c4 >= KV) return;
#pragma unroll
    for (int j = 0; j < 4; ++j) {
        int k = c4 + j;
        float v = (k < KREAL) ? W[(size_t)row * KREAL + k] * 1024.f : 0.f;
        _Float16 h = (_Float16)v;
        W0[(size_t)row * KV + k] = h;
        W1[(size_t)row * KV + k] = (_Float16)(v - (float)h);
    }
}

// ---------------- K1: x = relu(concat(enc, ent) @ W^T + b) via fp32-emulation-on-fp16-MFMA
// 128x128 tile, BK=64, 256 thr (4 waves, 2x2 of 64x64), 3 MFMA products into one fp32 acc.
// A staged from fp32 enc (split in-register, scaled by 32); ent gathered inline on last tile.
// LDS XOR-swizzle: byte ^= (row&7)<<4  (conflict-free ds_read_b128 fragments).
__global__ __launch_bounds__(256, 2) void fc1_mfma(
    const float* __restrict__ enc, const int* __restrict__ ex,
    const float* __restrict__ table,
    const _Float16* __restrict__ W0, const _Float16* __restrict__ W1,
    const float* __restrict__ bias, float* __restrict__ xout)
{
    __shared__ char lds[65536];
    char* sA0 = lds;
    char* sA1 = lds + 16384;
    char* sW0 = lds + 32768;
    char* sW1 = lds + 49152;
    const int t = threadIdx.x;
    const int l = t & 63;
    const int w = t >> 6;
    const int wr = w >> 1, wc = w & 1;
    const int bm0 = blockIdx.x * 128;
    const int bn0 = blockIdx.y * 128;

    f32x4 acc[4][4];
#pragma unroll
    for (int i = 0; i < 4; ++i)
#pragma unroll
        for (int j = 0; j < 4; ++j) acc[i][j] = (f32x4){0.f, 0.f, 0.f, 0.f};

    float4 pa[8];     // A prefetch (fp32, 128x64 per tile)
    uint4 pw0[4], pw1[4];  // W prefetch (fp16, 128x64 each)

    auto loadA = [&](int k0) {
        if (k0 < DB) {
#pragma unroll
            for (int c = 0; c < 8; ++c) {
                int idx = t + c * 256;
                int r = idx >> 4;
                int c4 = (idx & 15) << 2;
                pa[c] = *reinterpret_cast<const float4*>(enc + (size_t)(bm0 + r) * DB + k0 + c4);
            }
        } else {  // last tile: cols 768..831 = ent gather (e<50) else 0
#pragma unroll
            for (int c = 0; c < 8; ++c) {
                int idx = t + c * 256;
                int r = idx >> 4;
                int c4 = (idx & 15) << 2;
                const int* exr = ex + (size_t)(bm0 + r) * 3;
                int i0 = exr[0] * 50, i1 = exr[1] * 50, i2 = exr[2] * 50;
                float vv[4];
#pragma unroll
                for (int j = 0; j < 4; ++j) {
                    int e = c4 + j;
                    vv[j] = (e < 50) ? (table[i0 + e] + table[i1 + e] + table[i2 + e]) : 0.f;
                }
                pa[c] = make_float4(vv[0], vv[1], vv[2], vv[3]);
            }
        }
    };
    auto loadW = [&](int k0) {
#pragma unroll
        for (int c = 0; c < 4; ++c) {
            int idx = t + c * 256;
            int r = idx >> 3;
            int h0 = (idx & 7) << 3;
            pw0[c] = *reinterpret_cast<const uint4*>(W0 + (size_t)(bn0 + r) * KV + k0 + h0);
            pw1[c] = *reinterpret_cast<const uint4*>(W1 + (size_t)(bn0 + r) * KV + k0 + h0);
        }
    };

    loadA(0); loadW(0);

    for (int kt = 0; kt < 13; ++kt) {
        __syncthreads();
        // ---- write staged tile to LDS (A: scale*32 + fp16 split in-register)
#pragma unroll
        for (int c = 0; c < 8; ++c) {
            int idx = t + c * 256;
            int r = idx >> 4;
            int b0 = (idx & 15) << 3;              // byte offset in 128B row
            int off = (r << 7) + (b0 ^ ((r & 7) << 4));
            float f0 = pa[c].x * 32.f, f1 = pa[c].y * 32.f;
            float f2 = pa[c].z * 32.f, f3 = pa[c].w * 32.f;
            _Float16 h0 = (_Float16)f0, h1 = (_Float16)f1, h2 = (_Float16)f2, h3 = (_Float16)f3;
            f16x4 hi = {h0, h1, h2, h3};
            f16x4 lo = {(_Float16)(f0 - (float)h0), (_Float16)(f1 - (float)h1),
                        (_Float16)(f2 - (float)h2), (_Float16)(f3 - (float)h3)};
            *reinterpret_cast<f16x4*>(sA0 + off) = hi;
            *reinterpret_cast<f16x4*>(sA1 + off) = lo;
        }
#pragma unroll
        for (int c = 0; c < 4; ++c) {
            int idx = t + c * 256;
            int r = idx >> 3;
            int b0 = (idx & 7) << 4;
            int off = (r << 7) + (b0 ^ ((r & 7) << 4));
            *reinterpret_cast<uint4*>(sW0 + off) = pw0[c];
            *reinterpret_cast<uint4*>(sW1 + off) = pw1[c];
        }
        __syncthreads();
        if (kt < 12) { loadA((kt + 1) * 64); loadW((kt + 1) * 64); }  // overlap with MFMA
        // ---- compute: 2 k-steps x 16 frag-pairs x 3 products
#pragma unroll
        for (int ks = 0; ks < 2; ++ks) {
            const int lr = l & 15;
            const int kb = ks * 64 + ((l >> 4) << 4);
            f16x8 a0f[4], a1f[4], b0f[4], b1f[4];
#pragma unroll
            for (int mf = 0; mf < 4; ++mf) {
                int r = wr * 64 + mf * 16 + lr;
                int off = (r << 7) + (kb ^ ((r & 7) << 4));
                a0f[mf] = *reinterpret_cast<const f16x8*>(sA0 + off);
                a1f[mf] = *reinterpret_cast<const f16x8*>(sA1 + off);
            }
#pragma unroll
            for (int nf = 0; nf < 4; ++nf) {
                int r = wc * 64 + nf * 16 + lr;
                int off = (r << 7) + (kb ^ ((r & 7) << 4));
                b0f[nf] = *reinterpret_cast<const f16x8*>(sW0 + off);
                b1f[nf] = *reinterpret_cast<const f16x8*>(sW1 + off);
            }
#pragma unroll
            for (int mf = 0; mf < 4; ++mf)
#pragma unroll
                for (int nf = 0; nf < 4; ++nf) {
                    acc[mf][nf] = __builtin_amdgcn_mfma_f32_16x16x32_f16(a0f[mf], b0f[nf], acc[mf][nf], 0, 0, 0);
                    acc[mf][nf] = __builtin_amdgcn_mfma_f32_16x16x32_f16(a1f[mf], b0f[nf], acc[mf][nf], 0, 0, 0);
                    acc[mf][nf] = __builtin_amdgcn_mfma_f32_16x16x32_f16(a0f[mf], b1f[nf], acc[mf][nf], 0, 0, 0);
                }
        }
    }

    // ---- epilogue: unscale (A*32 * W*1024 = 2^15), bias, relu
    const float inv = 1.0f / 32768.f;
#pragma unroll
    for (int nf = 0; nf < 4; ++nf) {
        int col = bn0 + wc * 64 + nf * 16 + (l & 15);
        float bv = bias[col];
#pragma unroll
        for (int mf = 0; mf < 4; ++mf) {
            int rbase = bm0 + wr * 64 + mf * 16 + ((l >> 4) << 2);
#pragma unroll
            for (int j = 0; j < 4; ++j) {
                float x = fmaxf(acc[mf][nf][j] * inv + bv, 0.f);
                xout[(size_t)(rbase + j) * DB + col] = x;
            }
        }
    }
}

// ---------------- K2: gathered trig GEMM + bias + argmax (fp32, unchanged from R6)
__global__ __launch_bounds__(256) void trig_kernel(
    const float* __restrict__ xfc, const int* __restrict__ head_idx,
    const float* __restrict__ Wt, const float* __restrict__ bt,
    float* __restrict__ logits, float* __restrict__ hat)
{
    __shared__ float Xs[32 * 36];
    __shared__ float Ws[32 * 80];
    __shared__ int srow[32];
    const int t = threadIdx.x;
    const int s0 = blockIdx.x * 32;
    if (t < 32) {
        int sg = s0 + t;
        int b = sg >> 9;
        srow[t] = (b << 9) + head_idx[sg];
    }
    __syncthreads();
    const int tx = t & 15, ty = t >> 4;
    float acc[2][5];
#pragma unroll
    for (int i = 0; i < 2; ++i)
#pragma unroll
        for (int m = 0; m < 5; ++m) acc[i][m] = 0.f;

    for (int k0 = 0; k0 < DB; k0 += 32) {
        {
            int r = t >> 3;
            int c4 = (t & 7) << 2;
            float4 v = *reinterpret_cast<const float4*>(xfc + (size_t)srow[r] * DB + k0 + c4);
            Xs[(c4 + 0) * 36 + r] = v.x;
            Xs[(c4 + 1) * 36 + r] = v.y;
            Xs[(c4 + 2) * 36 + r] = v.z;
            Xs[(c4 + 3) * 36 + r] = v.w;
        }
#pragma unroll
        for (int i = 0; i < 10; ++i) {
            int e = t + i * 256;
            int kk = e & 31;
            int n = e >> 5;
            float v = (n < TT) ? Wt[(size_t)n * DB + k0 + kk] : 0.f;
            Ws[kk * 80 + n] = v;
        }
        __syncthreads();
#pragma unroll
        for (int kk = 0; kk < 32; ++kk) {
            v2f xa = *reinterpret_cast<const v2f*>(Xs + kk * 36 + ty * 2);
            float wv[5];
#pragma unroll
            for (int m = 0; m < 5; ++m) wv[m] = Ws[kk * 80 + tx + 16 * m];
#pragma unroll
            for (int m = 0; m < 5; ++m) {
                acc[0][m] += xa.x * wv[m];
                acc[1][m] += xa.y * wv[m];
            }
        }
        __syncthreads();
    }
#pragma unroll
    for (int i = 0; i < 2; ++i) {
        int row = s0 + ty * 2 + i;
        float bestv = -1e38f;
        int besti = 0;
#pragma unroll
        for (int m = 0; m < 5; ++m) {
            int col = tx + 16 * m;
            float v = -1e38f;
            if (col < TT) {
                v = acc[i][m] + bt[col];
                logits[(size_t)row * TT + col] = v;
            }
            if (v > bestv) { bestv = v; besti = col; }
        }
#pragma unroll
        for (int off = 8; off > 0; off >>= 1) {
            float ov = __shfl_xor(bestv, off, 16);
            int oi = __shfl_xor(besti, off, 16);
            if (ov > bestv || (ov == bestv && oi < besti)) { bestv = ov; besti = oi; }
        }
        if (tx == 0) hat[row] = (float)besti;
    }
}

// ---------------- K3a: span-mean pooling -> pooled[64][24][768]
__global__ __launch_bounds__(256) void pool_kernel(
    const float* __restrict__ xfc, const int* __restrict__ head_idx,
    const int* __restrict__ cand_spans, const int* __restrict__ trig_spans,
    float* __restrict__ pooled)
{
    const int b = blockIdx.x;
    __shared__ int rows_s[24][8];
    __shared__ int lens[24];
    __shared__ float invlen[24];
    const int t = threadIdx.x;
    if (t < 24) {
        const int* sp = (t < 8) ? (trig_spans + (b * 8 + t) * 2)
                                : (cand_spans + (b * 16 + (t - 8)) * 2);
        int st = sp[0], en = sp[1];
        int len = en - st;
        if (len < 0) len = 0;
        if (len > 8) len = 8;
        lens[t] = len;
        invlen[t] = 1.f / (float)(len > 0 ? len : 1);
        for (int p = 0; p < len; ++p)
            rows_s[t][p] = (b << 9) + head_idx[(b << 9) + st + p];
    }
    __syncthreads();
    for (int idx = t; idx < 24 * DB; idx += 256) {
        int n = idx / DB;
        int d = idx - n * DB;
        int len = lens[n];
        float s = 0.f;
        for (int p = 0; p < len; ++p)
            s += xfc[(size_t)rows_s[n][p] * DB + d];
        pooled[((size_t)b * 24 + n) * DB + d] = s * invlen[n];
    }
}

// ---------------- K3b: argument_hidden broadcast write [64][8][16][1536]
__global__ __launch_bounds__(256) void arg_kernel(
    const float* __restrict__ pooled, float* __restrict__ out2)
{
    int g = blockIdx.x * 256 + threadIdx.x;
    int b = g / 49152;
    int rem = g - b * 49152;
    int pair = rem / 384;
    int off4 = rem - pair * 384;
    int ti = pair >> 4;
    int c = pair & 15;
    int col = off4 << 2;
    const float* src;
    if (col < DB) src = pooled + ((size_t)(b * 24 + ti)) * DB + col;
    else          src = pooled + ((size_t)(b * 24 + 8 + c)) * DB + (col - DB);
    float4 v = *reinterpret_cast<const float4*>(src);
    *reinterpret_cast<float4*>(out2 + ((size_t)g << 2)) = v;
}

extern "C" void kernel_launch(void* const* d_in, const int* in_sizes, int n_in,
                              void* d_out, int out_size, void* d_ws, size_t ws_size,
                              hipStream_t stream)
{
    const float* enc   = (const float*)d_in[0];
    const float* table = (const float*)d_in[1];
    const float* fc1w  = (const float*)d_in[2];
    const float* fc1b  = (const float*)d_in[3];
    const float* trigw = (const float*)d_in[4];
    const float* trigb = (const float*)d_in[5];
    const int*   ex    = (const int*)d_in[6];
    const int*   hidx  = (const int*)d_in[7];
    const int*   cspan = (const int*)d_in[8];
    const int*   tspan = (const int*)d_in[9];

    float* out0 = (float*)d_out;
    float* out1 = out0 + (size_t)BS_TOTAL * TT;
    float* out2 = out1 + BS_TOTAL;

    float* ws_xfc  = (float*)d_ws;                          // [32768][768] fp32
    float* ws_pool = ws_xfc + (size_t)BS_TOTAL * DB;        // [64][24][768]
    _Float16* wsW0 = (_Float16*)(ws_pool + (size_t)64 * 24 * DB);  // [768][832] fp16
    _Float16* wsW1 = wsW0 + (size_t)DB * KV;

    splitw_kernel<<<dim3(DB), dim3(256), 0, stream>>>(fc1w, wsW0, wsW1);
    fc1_mfma<<<dim3(BS_TOTAL / 128, DB / 128), dim3(256), 0, stream>>>(
        enc, ex, table, wsW0, wsW1, fc1b, ws_xfc);
    trig_kernel<<<dim3(BS_TOTAL / 32), dim3(256), 0, stream>>>(ws_xfc, hidx, trigw, trigb, out0, out1);
    pool_kernel<<<dim3(64), dim3(256), 0, stream>>>(ws_xfc, hidx, cspan, tspan, ws_pool);
    arg_kernel<<<dim3(3145728 / 256), dim3(256), 0, stream>>>(ws_pool, out2);
}